// Round 7
// baseline (230.148 us; speedup 1.0000x reference)
//
#include <hip/hip_runtime.h>
#include <math.h>

#define NPTS 11
#define NSTEPS 10
#define METRIC_FLOOR 0.1f

typedef float v2f __attribute__((ext_vector_type(2)));

#define L2E 1.44269504088896340736f
#define LN2 0.69314718055994530942f

// Lane-pair exchange via DPP quad_perm [1,0,3,2] (0xB1): swaps lanes 0<->1,
// 2<->3 within each quad. Pure VALU, no LDS pipe.
static __device__ __forceinline__ float pswap(float x) {
    int i = __builtin_bit_cast(int, x);
    i = __builtin_amdgcn_mov_dpp(i, 0xB1, 0xF, 0xF, true);
    return __builtin_bit_cast(float, i);
}

static __device__ __forceinline__ float fast_tanh(float x) {
    float e = __builtin_amdgcn_exp2f(x * (2.0f * L2E));
    return fmaf(-2.0f, __builtin_amdgcn_rcpf(e + 1.0f), 1.0f);
}

// Per-lane HALF of the metric-MLP small weights (this lane's 8 neurons /
// 8 output columns). Lane-dependent values -> VGPRs.
struct MWh {
    float w1c[8], w1l[8], b1v[8], b2v[8], w3v[8];
};

// ---------------------------------------------------------------------------
// metric0h: value only, lane-pair split. Each lane: 8 hidden neurons (L1),
// partner's h via pswap, 8 output columns of L2, partial z reduced via pswap.
// rowsA = own 8 rows (own col-slice), rowsB = partner rows (own col-slice).
// ---------------------------------------------------------------------------
static __device__ __forceinline__ float metric0h(
    float c, float lam, const MWh& mw,
    const float* __restrict__ rowsA, const float* __restrict__ rowsB,
    float b3v)
{
    float ho[8];
#pragma unroll
    for (int k = 0; k < 8; ++k) {
        float u = fmaf(c, mw.w1c[k], fmaf(lam, mw.w1l[k], mw.b1v[k]));
        ho[k] = fast_tanh(u);
    }
    float hx[8];
#pragma unroll
    for (int k = 0; k < 8; ++k) hx[k] = pswap(ho[k]);

    v2f U[4];
#pragma unroll
    for (int jp = 0; jp < 4; ++jp) U[jp] = (v2f){mw.b2v[2*jp], mw.b2v[2*jp+1]};

#pragma unroll 2
    for (int k = 0; k < 8; ++k) {
        const float4* r = reinterpret_cast<const float4*>(rowsA + k * 16);
        float4 w0 = r[0], w1 = r[1];
        v2f hh = (v2f){ho[k], ho[k]};
        U[0] = __builtin_elementwise_fma((v2f){w0.x, w0.y}, hh, U[0]);
        U[1] = __builtin_elementwise_fma((v2f){w0.z, w0.w}, hh, U[1]);
        U[2] = __builtin_elementwise_fma((v2f){w1.x, w1.y}, hh, U[2]);
        U[3] = __builtin_elementwise_fma((v2f){w1.z, w1.w}, hh, U[3]);
    }
#pragma unroll 2
    for (int k = 0; k < 8; ++k) {
        const float4* r = reinterpret_cast<const float4*>(rowsB + k * 16);
        float4 w0 = r[0], w1 = r[1];
        v2f hh = (v2f){hx[k], hx[k]};
        U[0] = __builtin_elementwise_fma((v2f){w0.x, w0.y}, hh, U[0]);
        U[1] = __builtin_elementwise_fma((v2f){w0.z, w0.w}, hh, U[1]);
        U[2] = __builtin_elementwise_fma((v2f){w1.x, w1.y}, hh, U[2]);
        U[3] = __builtin_elementwise_fma((v2f){w1.z, w1.w}, hh, U[3]);
    }

    float zp = 0.0f;
#pragma unroll
    for (int jp = 0; jp < 4; ++jp) {
#pragma unroll
        for (int kk = 0; kk < 2; ++kk)
            zp = fmaf(fast_tanh(U[jp][kk]), mw.w3v[2*jp+kk], zp);
    }
    float z = b3v + zp + pswap(zp);

    float az = fabsf(z);
    float em = __builtin_amdgcn_exp2f(-az * L2E);
    float sp = fmaxf(z, 0.0f) + __builtin_amdgcn_logf(1.0f + em) * LN2;
    return sp + METRIC_FLOOR;
}

// ---------------------------------------------------------------------------
// gamma1h: Gamma = 0.5*(dg/dc)/g, lane-pair split (value + d/dc chains).
// Both lanes reconstruct identical full (z,dz) -> identical G (lockstep).
// ---------------------------------------------------------------------------
static __device__ __forceinline__ float gamma1h(
    float c, float lam, const MWh& mw,
    const float* __restrict__ rowsA, const float* __restrict__ rowsB,
    float b3v)
{
    float ho[8], po[8];
#pragma unroll
    for (int k = 0; k < 8; ++k) {
        float a  = mw.w1c[k];
        float u  = fmaf(c, a, fmaf(lam, mw.w1l[k], mw.b1v[k]));
        float t0 = fast_tanh(u);
        float s  = fmaf(-t0, t0, 1.0f);
        ho[k] = t0;
        po[k] = s * a;
    }
    float hx[8], px[8];
#pragma unroll
    for (int k = 0; k < 8; ++k) { hx[k] = pswap(ho[k]); px[k] = pswap(po[k]); }

    v2f U[4], DU[4];
#pragma unroll
    for (int jp = 0; jp < 4; ++jp) {
        U[jp]  = (v2f){mw.b2v[2*jp], mw.b2v[2*jp+1]};
        DU[jp] = (v2f){0.0f, 0.0f};
    }
#pragma unroll 2
    for (int k = 0; k < 8; ++k) {
        const float4* r = reinterpret_cast<const float4*>(rowsA + k * 16);
        float4 w0 = r[0], w1 = r[1];
        v2f hh = (v2f){ho[k], ho[k]};
        v2f pp = (v2f){po[k], po[k]};
        v2f wa = (v2f){w0.x, w0.y}, wb = (v2f){w0.z, w0.w};
        v2f wc = (v2f){w1.x, w1.y}, wd = (v2f){w1.z, w1.w};
        U[0]  = __builtin_elementwise_fma(wa, hh, U[0]);
        DU[0] = __builtin_elementwise_fma(wa, pp, DU[0]);
        U[1]  = __builtin_elementwise_fma(wb, hh, U[1]);
        DU[1] = __builtin_elementwise_fma(wb, pp, DU[1]);
        U[2]  = __builtin_elementwise_fma(wc, hh, U[2]);
        DU[2] = __builtin_elementwise_fma(wc, pp, DU[2]);
        U[3]  = __builtin_elementwise_fma(wd, hh, U[3]);
        DU[3] = __builtin_elementwise_fma(wd, pp, DU[3]);
    }
#pragma unroll 2
    for (int k = 0; k < 8; ++k) {
        const float4* r = reinterpret_cast<const float4*>(rowsB + k * 16);
        float4 w0 = r[0], w1 = r[1];
        v2f hh = (v2f){hx[k], hx[k]};
        v2f pp = (v2f){px[k], px[k]};
        v2f wa = (v2f){w0.x, w0.y}, wb = (v2f){w0.z, w0.w};
        v2f wc = (v2f){w1.x, w1.y}, wd = (v2f){w1.z, w1.w};
        U[0]  = __builtin_elementwise_fma(wa, hh, U[0]);
        DU[0] = __builtin_elementwise_fma(wa, pp, DU[0]);
        U[1]  = __builtin_elementwise_fma(wb, hh, U[1]);
        DU[1] = __builtin_elementwise_fma(wb, pp, DU[1]);
        U[2]  = __builtin_elementwise_fma(wc, hh, U[2]);
        DU[2] = __builtin_elementwise_fma(wc, pp, DU[2]);
        U[3]  = __builtin_elementwise_fma(wd, hh, U[3]);
        DU[3] = __builtin_elementwise_fma(wd, pp, DU[3]);
    }

    float zp = 0.0f, dzp = 0.0f;
#pragma unroll
    for (int jp = 0; jp < 4; ++jp) {
#pragma unroll
        for (int kk = 0; kk < 2; ++kk) {
            float u  = U[jp][kk];
            float du = DU[jp][kk];
            float t0 = fast_tanh(u);
            float s  = fmaf(-t0, t0, 1.0f);
            float w3 = mw.w3v[2*jp+kk];
            zp  = fmaf(t0, w3, zp);
            dzp = fmaf(s * du, w3, dzp);
        }
    }
    float z  = b3v + zp + pswap(zp);
    float dz = dzp + pswap(dzp);

    float az  = fabsf(z);
    float em  = __builtin_amdgcn_exp2f(-az * L2E);
    float sp  = fmaxf(z, 0.0f) + __builtin_amdgcn_logf(1.0f + em) * LN2;
    float sig = __builtin_amdgcn_rcpf(1.0f + __builtin_amdgcn_exp2f(-z * L2E));
    float g   = sp + METRIC_FLOOR;
    return 0.5f * (sig * dz) * __builtin_amdgcn_rcpf(g);
}

extern "C" __global__ __launch_bounds__(256, 2)
void geodesic_kernel(const float* __restrict__ gc0, const float* __restrict__ gc1,
                     const float* __restrict__ glam,
                     const float* __restrict__ W1, const float* __restrict__ b1,
                     const float* __restrict__ W2, const float* __restrict__ b2,
                     const float* __restrict__ W3, const float* __restrict__ b3,
                     const float* __restrict__ D1, const float* __restrict__ d1,
                     const float* __restrict__ D2, const float* __restrict__ d2,
                     float* __restrict__ out, int n)
{
    __shared__ __align__(16) float sW2[256];
    __shared__ __align__(16) float sD1[6 * 64];
    __shared__ __align__(16) float sd1[64];
    __shared__ __align__(16) float sD2[64];

    const int t = threadIdx.x;
    sW2[t] = W2[t];
    for (int i = t; i < 384; i += 256) sD1[i] = D1[i];
    if (t >= 64 && t < 128) sd1[t - 64] = d1[t - 64];
    if (t >= 128 && t < 192) sD2[t - 128] = D2[t - 128];
    __syncthreads();

    const int gid  = blockIdx.x * blockDim.x + t;
    const int e    = gid >> 1;       // element index (2 lanes per element)
    const int half = gid & 1;        // which 8-neuron half this lane owns
    if (e >= n) return;

    // This lane's half of the small weights.
    MWh mw;
    {
        const int b = 8 * half;
#pragma unroll
        for (int k = 0; k < 8; ++k) {
            mw.w1c[k] = W1[b + k];
            mw.w1l[k] = W1[16 + b + k];
            mw.b1v[k] = b1[b + k];
            mw.b2v[k] = b2[b + k];
            mw.w3v[k] = W3[b + k];
        }
    }
    const float b3v = b3[0];
    const float d2v = d2[0];

    // W2 row slices: own rows x own col-slice, partner rows x own col-slice.
    const float* rowsA = sW2 + (8 * half) * 16 + 8 * half;
    const float* rowsB = sW2 + (8 * (1 - half)) * 16 + 8 * half;

    const float c0  = gc0[e];
    const float c1  = gc1[e];
    const float lam = glam[e];

    const float dt  = 1.0f / (float)(NPTS - 1);
    const float hdt = 0.5f * dt;
    const float dt6 = dt / 6.0f;

    // ---------------- Analytic init: sqrt(g)*v conserved --------------------
    const float mqm = 0.5f * (c0 + c1), mqr = 0.5f * (c1 - c0);
    float K;
    {
        const float x0 = 0.1834346424956498f, w0 = 0.3626837833783620f;
        const float x1 = 0.5255324099163290f, w1 = 0.3137066458778873f;
        const float x2 = 0.7966664774136267f, w2 = 0.2223810344533745f;
        const float x3 = 0.9602898564975363f, w3q = 0.1012285362903763f;
        float s0 = sqrtf(metric0h(fmaf(mqr,  x0, mqm), lam, mw, rowsA, rowsB, b3v))
                 + sqrtf(metric0h(fmaf(mqr, -x0, mqm), lam, mw, rowsA, rowsB, b3v));
        float s1 = sqrtf(metric0h(fmaf(mqr,  x1, mqm), lam, mw, rowsA, rowsB, b3v))
                 + sqrtf(metric0h(fmaf(mqr, -x1, mqm), lam, mw, rowsA, rowsB, b3v));
        float s2 = sqrtf(metric0h(fmaf(mqr,  x2, mqm), lam, mw, rowsA, rowsB, b3v))
                 + sqrtf(metric0h(fmaf(mqr, -x2, mqm), lam, mw, rowsA, rowsB, b3v));
        float s3 = sqrtf(metric0h(fmaf(mqr,  x3, mqm), lam, mw, rowsA, rowsB, b3v))
                 + sqrtf(metric0h(fmaf(mqr, -x3, mqm), lam, mw, rowsA, rowsB, b3v));
        K = w0 * s0 + w1 * s1 + w2 * s2 + w3q * s3;
    }
    const float g0   = metric0h(c0, lam, mw, rowsA, rowsB, b3v);
    const float rsg0 = rsqrtf(g0);
    float v0 = (mqr * K) * rsg0;

    // ---------------- Pass 1: plain integration -> residual -----------------
    {
        float c = c0, v = v0;
#pragma unroll 1
        for (int s = 0; s < NSTEPS; ++s) {
            float G1 = gamma1h(c, lam, mw, rowsA, rowsB, b3v);
            float k1c = v, k1v = -G1 * v * v;
            float c2 = c + hdt * k1c, v2 = v + hdt * k1v;
            float G2 = gamma1h(c2, lam, mw, rowsA, rowsB, b3v);
            float k2c = v2, k2v = -G2 * v2 * v2;
            float c3 = c + hdt * k2c, v3 = v + hdt * k2v;
            float G3 = gamma1h(c3, lam, mw, rowsA, rowsB, b3v);
            float k3c = v3, k3v = -G3 * v3 * v3;
            float c4 = c + dt * k3c, v4 = v + dt * k3v;
            float G4 = gamma1h(c4, lam, mw, rowsA, rowsB, b3v);
            float k4c = v4, k4v = -G4 * v4 * v4;
            c += dt6 * (k1c + 2.0f * k2c + 2.0f * k3c + k4c);
            v += dt6 * (k1v + 2.0f * k2v + 2.0f * k3v + k4v);
        }
        // Quasi-Newton with analytic Jacobian dcf/dv0 = sqrt(g0)/sqrt(g(cf)).
        float gcf = metric0h(c, lam, mw, rowsA, rowsB, b3v);
        v0 -= (c - c1) * sqrtf(gcf) * rsg0;
    }

    // ---------------- Pass 2: integration with path statistics --------------
    float csum, vsum, plen, vmax, cf;
    {
        float c = c0, v = v0;
        float cs = c0, vs = v0, pl = 0.0f, vm = fabsf(v0), cp = c0;
#pragma unroll 1
        for (int s = 0; s < NSTEPS; ++s) {
            float G1 = gamma1h(c, lam, mw, rowsA, rowsB, b3v);
            float k1c = v, k1v = -G1 * v * v;
            float c2 = c + hdt * k1c, v2 = v + hdt * k1v;
            float G2 = gamma1h(c2, lam, mw, rowsA, rowsB, b3v);
            float k2c = v2, k2v = -G2 * v2 * v2;
            float c3 = c + hdt * k2c, v3 = v + hdt * k2v;
            float G3 = gamma1h(c3, lam, mw, rowsA, rowsB, b3v);
            float k3c = v3, k3v = -G3 * v3 * v3;
            float c4 = c + dt * k3c, v4 = v + dt * k3v;
            float G4 = gamma1h(c4, lam, mw, rowsA, rowsB, b3v);
            float k4c = v4, k4v = -G4 * v4 * v4;
            c += dt6 * (k1c + 2.0f * k2c + 2.0f * k3c + k4c);
            v += dt6 * (k1v + 2.0f * k2v + 2.0f * k3v + k4v);
            cs += c; vs += v;
            pl += fabsf(c - cp); cp = c;
            vm = fmaxf(vm, fabsf(v));
        }
        csum = cs; vsum = vs; plen = pl; vmax = vm; cf = c;
    }

    // ---------------- Decoder: feats(6) -> 64 tanh -> 1 (split 32/32) -------
    const float inv_npts = 1.0f / (float)NPTS;
    const float f0 = csum * inv_npts;
    const float f1 = cf;
    const float f2 = plen;
    const float f3 = vsum * inv_npts;
    const float f4 = vmax;
    const float f5 = lam;

    const int jb = 32 * half;
    float accp = 0.0f;
#pragma unroll 4
    for (int k = 0; k < 32; ++k) {
        int j = jb + k;
        float u = sd1[j];
        u = fmaf(f0, sD1[0 * 64 + j], u);
        u = fmaf(f1, sD1[1 * 64 + j], u);
        u = fmaf(f2, sD1[2 * 64 + j], u);
        u = fmaf(f3, sD1[3 * 64 + j], u);
        u = fmaf(f4, sD1[4 * 64 + j], u);
        u = fmaf(f5, sD1[5 * 64 + j], u);
        accp = fmaf(fast_tanh(u), sD2[j], accp);
    }
    float acc = d2v + accp + pswap(accp);
    if (half == 0) out[e] = acc;
}

extern "C" void kernel_launch(void* const* d_in, const int* in_sizes, int n_in,
                              void* d_out, int out_size, void* d_ws, size_t ws_size,
                              hipStream_t stream) {
    const float* c_source   = (const float*)d_in[0];
    const float* c_target   = (const float*)d_in[1];
    const float* wavelength = (const float*)d_in[2];
    const float* W1 = (const float*)d_in[3];
    const float* b1 = (const float*)d_in[4];
    const float* W2 = (const float*)d_in[5];
    const float* b2 = (const float*)d_in[6];
    const float* W3 = (const float*)d_in[7];
    const float* b3 = (const float*)d_in[8];
    const float* D1 = (const float*)d_in[9];
    const float* d1 = (const float*)d_in[10];
    const float* D2 = (const float*)d_in[11];
    const float* d2 = (const float*)d_in[12];
    float* out = (float*)d_out;

    const int n = in_sizes[0];
    const int block = 256;
    const long long threads = 2LL * n;           // 2 lanes per element
    const int grid = (int)((threads + block - 1) / block);
    hipLaunchKernelGGL(geodesic_kernel, dim3(grid), dim3(block), 0, stream,
                       c_source, c_target, wavelength,
                       W1, b1, W2, b2, W3, b3, D1, d1, D2, d2, out, n);
}

// Round 8
// 87.503 us; speedup vs baseline: 2.6302x; 2.6302x over previous
//
#include <hip/hip_runtime.h>
#include <math.h>

#define NPTS 11
#define NSTEPS 10
#define METRIC_FLOOR 0.1f

typedef float v2f __attribute__((ext_vector_type(2)));

#define L2E 1.44269504088896340736f
#define LN2 0.69314718055994530942f

// Small metric-MLP weights held per-thread (uniform -> scalarized to SGPRs).
struct MW {
    float w1c[16], w1l[16], b1v[16], b2v[16], w3v[16];
};

static __device__ __forceinline__ float fast_tanh(float x) {
    float e = __builtin_amdgcn_exp2f(x * (2.0f * L2E));
    return fmaf(-2.0f, __builtin_amdgcn_rcpf(e + 1.0f), 1.0f);
}

// ---------------------------------------------------------------------------
// metric0: value only (quadrature init)
// ---------------------------------------------------------------------------
static __device__ __forceinline__ float metric0(
    float c, float lam, const MW& mw, const float* __restrict__ sW2, float b3v)
{
    float h1[16];
#pragma unroll
    for (int j = 0; j < 16; ++j) {
        float u = fmaf(c, mw.w1c[j], fmaf(lam, mw.w1l[j], mw.b1v[j]));
        h1[j] = fast_tanh(u);
    }
    v2f U[8];
#pragma unroll
    for (int jp = 0; jp < 8; ++jp) U[jp] = (v2f){mw.b2v[2*jp], mw.b2v[2*jp+1]};
#pragma unroll 2
    for (int i = 0; i < 16; ++i) {
        const float4* wrow4 = reinterpret_cast<const float4*>(sW2 + i * 16);
        v2f hh = (v2f){h1[i], h1[i]};
#pragma unroll
        for (int q4 = 0; q4 < 4; ++q4) {
            float4 w4 = wrow4[q4];
            U[2*q4]   = __builtin_elementwise_fma((v2f){w4.x, w4.y}, hh, U[2*q4]);
            U[2*q4+1] = __builtin_elementwise_fma((v2f){w4.z, w4.w}, hh, U[2*q4+1]);
        }
    }
    float z = b3v;
#pragma unroll
    for (int jp = 0; jp < 8; ++jp) {
#pragma unroll
        for (int k = 0; k < 2; ++k)
            z = fmaf(fast_tanh(U[jp][k]), mw.w3v[2*jp+k], z);
    }
    float az = fabsf(z);
    float em = __builtin_amdgcn_exp2f(-az * L2E);
    float sp = fmaxf(z, 0.0f) + __builtin_amdgcn_logf(1.0f + em) * LN2;
    return sp + METRIC_FLOOR;
}

// ---------------------------------------------------------------------------
// gamma1: Gamma = 0.5*(dg/dc)/g  (the single integration pass)
// ---------------------------------------------------------------------------
static __device__ __forceinline__ float gamma1(
    float c, float lam, const MW& mw, const float* __restrict__ sW2, float b3v)
{
    float h1[16], p1[16];
#pragma unroll
    for (int j = 0; j < 16; ++j) {
        float a  = mw.w1c[j];
        float u  = fmaf(c, a, fmaf(lam, mw.w1l[j], mw.b1v[j]));
        float t0 = fast_tanh(u);
        float s  = fmaf(-t0, t0, 1.0f);
        h1[j] = t0;
        p1[j] = s * a;
    }

    v2f U[8], DU[8];
#pragma unroll
    for (int jp = 0; jp < 8; ++jp) {
        U[jp]  = (v2f){mw.b2v[2*jp], mw.b2v[2*jp+1]};
        DU[jp] = (v2f){0.0f, 0.0f};
    }
#pragma unroll 2
    for (int i = 0; i < 16; ++i) {
        const float4* wrow4 = reinterpret_cast<const float4*>(sW2 + i * 16);
        v2f hh = (v2f){h1[i], h1[i]};
        v2f pp = (v2f){p1[i], p1[i]};
#pragma unroll
        for (int q4 = 0; q4 < 4; ++q4) {
            float4 w4 = wrow4[q4];
            v2f wa = (v2f){w4.x, w4.y};
            v2f wb = (v2f){w4.z, w4.w};
            int jp = 2 * q4;
            U[jp]    = __builtin_elementwise_fma(wa, hh, U[jp]);
            DU[jp]   = __builtin_elementwise_fma(wa, pp, DU[jp]);
            U[jp+1]  = __builtin_elementwise_fma(wb, hh, U[jp+1]);
            DU[jp+1] = __builtin_elementwise_fma(wb, pp, DU[jp+1]);
        }
    }

    float z = b3v, dz = 0.0f;
#pragma unroll
    for (int jp = 0; jp < 8; ++jp) {
#pragma unroll
        for (int k = 0; k < 2; ++k) {
            float u  = U[jp][k];
            float du = DU[jp][k];
            float t0 = fast_tanh(u);
            float s  = fmaf(-t0, t0, 1.0f);
            float w3 = mw.w3v[2*jp+k];
            z  = fmaf(t0, w3, z);
            dz = fmaf(s * du, w3, dz);
        }
    }

    float az  = fabsf(z);
    float em  = __builtin_amdgcn_exp2f(-az * L2E);
    float sp  = fmaxf(z, 0.0f) + __builtin_amdgcn_logf(1.0f + em) * LN2;
    float sig = __builtin_amdgcn_rcpf(1.0f + __builtin_amdgcn_exp2f(-z * L2E));
    float g   = sp + METRIC_FLOOR;
    return 0.5f * (sig * dz) * __builtin_amdgcn_rcpf(g);
}

extern "C" __global__ __launch_bounds__(256, 1)
void geodesic_kernel(const float* __restrict__ gc0, const float* __restrict__ gc1,
                     const float* __restrict__ glam,
                     const float* __restrict__ W1, const float* __restrict__ b1,
                     const float* __restrict__ W2, const float* __restrict__ b2,
                     const float* __restrict__ W3, const float* __restrict__ b3,
                     const float* __restrict__ D1, const float* __restrict__ d1,
                     const float* __restrict__ D2, const float* __restrict__ d2,
                     float* __restrict__ out, int n)
{
    __shared__ __align__(16) float sW2[256];
    __shared__ __align__(16) float sD1[6 * 64];
    __shared__ __align__(16) float sd1[64];
    __shared__ __align__(16) float sD2[64];

    const int t = threadIdx.x;
    sW2[t] = W2[t];
    for (int i = t; i < 384; i += 256) sD1[i] = D1[i];
    if (t >= 64 && t < 128) sd1[t - 64] = d1[t - 64];
    if (t >= 128 && t < 192) sD2[t - 128] = D2[t - 128];
    __syncthreads();

    const int idx = blockIdx.x * blockDim.x + t;
    if (idx >= n) return;

    MW mw;
#pragma unroll
    for (int j = 0; j < 16; ++j) {
        mw.w1c[j] = W1[j];
        mw.w1l[j] = W1[16 + j];
        mw.b1v[j] = b1[j];
        mw.b2v[j] = b2[j];
        mw.w3v[j] = W3[j];
    }
    const float b3v = b3[0];
    const float d2v = d2[0];

    const float c0  = gc0[idx];
    const float c1  = gc1[idx];
    const float lam = glam[idx];

    const float dt  = 1.0f / (float)(NPTS - 1);
    const float hdt = 0.5f * dt;
    const float dt6 = dt / 6.0f;

    // ---------------- Analytic init: sqrt(g)*v conserved --------------------
    // v0 = (Integral_{c0}^{c1} sqrt(g) dc) / sqrt(g(c0)), 8-pt Gauss-Legendre.
    const float mqm = 0.5f * (c0 + c1), mqr = 0.5f * (c1 - c0);
    float K;
    {
        const float x0 = 0.1834346424956498f, w0 = 0.3626837833783620f;
        const float x1 = 0.5255324099163290f, w1 = 0.3137066458778873f;
        const float x2 = 0.7966664774136267f, w2 = 0.2223810344533745f;
        const float x3 = 0.9602898564975363f, w3q = 0.1012285362903763f;
        float s0 = sqrtf(metric0(fmaf(mqr,  x0, mqm), lam, mw, sW2, b3v))
                 + sqrtf(metric0(fmaf(mqr, -x0, mqm), lam, mw, sW2, b3v));
        float s1 = sqrtf(metric0(fmaf(mqr,  x1, mqm), lam, mw, sW2, b3v))
                 + sqrtf(metric0(fmaf(mqr, -x1, mqm), lam, mw, sW2, b3v));
        float s2 = sqrtf(metric0(fmaf(mqr,  x2, mqm), lam, mw, sW2, b3v))
                 + sqrtf(metric0(fmaf(mqr, -x2, mqm), lam, mw, sW2, b3v));
        float s3 = sqrtf(metric0(fmaf(mqr,  x3, mqm), lam, mw, sW2, b3v))
                 + sqrtf(metric0(fmaf(mqr, -x3, mqm), lam, mw, sW2, b3v));
        K = w0 * s0 + w1 * s1 + w2 * s2 + w3q * s3;
    }
    const float g0 = metric0(c0, lam, mw, sW2, b3v);
    const float v0i = (mqr * K) * rsqrtf(g0);

    // ---------------- Single RK4 pass + stats + sensitivity accumulators ----
    // cs2 = sum_i t_i*v_i (nodes 1..10), va = sum_i t_i*a_i (a = dv/dt);
    // a at node s is this step's k1v (exact); node 10 uses last k4v (~O(dt^3)).
    float csum, vsum, plen, vmax, cf, vf, cs2, va;
    {
        float c = c0, v = v0i;
        float cs = c0, vs = v0i, pl = 0.0f, vm = fabsf(v0i), cp = c0;
        float c2sum = 0.0f, vasum = 0.0f, k4v_last = 0.0f;
#pragma unroll 1
        for (int s = 0; s < NSTEPS; ++s) {
            float G1 = gamma1(c, lam, mw, sW2, b3v);
            float k1c = v, k1v = -G1 * v * v;
            vasum = fmaf((float)s * dt, k1v, vasum);      // t_s * a_s  (s=0 -> 0)
            float c2 = c + hdt * k1c, v2 = v + hdt * k1v;
            float G2 = gamma1(c2, lam, mw, sW2, b3v);
            float k2c = v2, k2v = -G2 * v2 * v2;
            float c3 = c + hdt * k2c, v3 = v + hdt * k2v;
            float G3 = gamma1(c3, lam, mw, sW2, b3v);
            float k3c = v3, k3v = -G3 * v3 * v3;
            float c4 = c + dt * k3c, v4 = v + dt * k3v;
            float G4 = gamma1(c4, lam, mw, sW2, b3v);
            float k4c = v4, k4v = -G4 * v4 * v4;
            c += dt6 * (k1c + 2.0f * k2c + 2.0f * k3c + k4c);
            v += dt6 * (k1v + 2.0f * k2v + 2.0f * k3v + k4v);
            cs += c; vs += v;
            c2sum = fmaf((float)(s + 1) * dt, v, c2sum);  // t_{s+1} * v_{s+1}
            pl += fabsf(c - cp); cp = c;
            vm = fmaxf(vm, fabsf(v));
            k4v_last = k4v;
        }
        vasum += k4v_last;                                // t_10 = 1.0, a_10 ~ k4v
        csum = cs; vsum = vs; plen = pl; vmax = vm; cf = c; vf = v;
        cs2 = c2sum; va = vasum;
    }

    // ---------------- First-order correction to the Newton root -------------
    // eps = delta_v0 / v0; dcf = eps*vf  =>  eps = (c1 - cf)/vf.
    float vf_safe = (fabsf(vf) < 1e-6f) ? ((vf >= 0.0f) ? 1e-6f : -1e-6f) : vf;
    float eps = (c1 - cf) * __builtin_amdgcn_rcpf(vf_safe);
    float csum_c = fmaf(eps, cs2, csum);                  // d csum = eps * sum t_i v_i
    float vsum_c = fmaf(eps, vsum + va, vsum);            // d vsum = eps*(vsum + sum t_i a_i)
    float plen_c = plen + ((vf >= 0.0f) ? (c1 - cf) : (cf - c1)); // telescoping
    float vmax_c = fmaf(eps, vmax, vmax);                 // |v| scales by (1+eps)
    float cf_c   = cf + eps * vf_safe;                    // == c1 (residual zeroed)

    // ---------------- Decoder: feats(6) -> 64 tanh -> 1 ----------------
    const float inv_npts = 1.0f / (float)NPTS;
    const float f0 = csum_c * inv_npts;
    const float f1 = cf_c;
    const float f2 = plen_c;
    const float f3 = vsum_c * inv_npts;
    const float f4 = vmax_c;
    const float f5 = lam;

    float acc = d2v;
#pragma unroll 4
    for (int j = 0; j < 64; ++j) {
        float u = sd1[j];
        u = fmaf(f0, sD1[0 * 64 + j], u);
        u = fmaf(f1, sD1[1 * 64 + j], u);
        u = fmaf(f2, sD1[2 * 64 + j], u);
        u = fmaf(f3, sD1[3 * 64 + j], u);
        u = fmaf(f4, sD1[4 * 64 + j], u);
        u = fmaf(f5, sD1[5 * 64 + j], u);
        acc = fmaf(fast_tanh(u), sD2[j], acc);
    }
    out[idx] = acc;
}

extern "C" void kernel_launch(void* const* d_in, const int* in_sizes, int n_in,
                              void* d_out, int out_size, void* d_ws, size_t ws_size,
                              hipStream_t stream) {
    const float* c_source   = (const float*)d_in[0];
    const float* c_target   = (const float*)d_in[1];
    const float* wavelength = (const float*)d_in[2];
    const float* W1 = (const float*)d_in[3];
    const float* b1 = (const float*)d_in[4];
    const float* W2 = (const float*)d_in[5];
    const float* b2 = (const float*)d_in[6];
    const float* W3 = (const float*)d_in[7];
    const float* b3 = (const float*)d_in[8];
    const float* D1 = (const float*)d_in[9];
    const float* d1 = (const float*)d_in[10];
    const float* D2 = (const float*)d_in[11];
    const float* d2 = (const float*)d_in[12];
    float* out = (float*)d_out;

    const int n = in_sizes[0];
    const int block = 256;
    const int grid  = (n + block - 1) / block;
    hipLaunchKernelGGL(geodesic_kernel, dim3(grid), dim3(block), 0, stream,
                       c_source, c_target, wavelength,
                       W1, b1, W2, b2, W3, b3, D1, d1, D2, d2, out, n);
}